// Round 13
// baseline (199.223 us; speedup 1.0000x reference)
//
#include <hip/hip_runtime.h>
#include <hip/hip_bf16.h>

typedef __attribute__((ext_vector_type(8))) short short8;
typedef __attribute__((ext_vector_type(4))) float f32x4;

#define MFMA16(a,b,c) __builtin_amdgcn_mfma_f32_16x16x32_bf16((a),(b),(c),0,0,0)

static __device__ __forceinline__ unsigned int f2bf(float f){
    unsigned int u = __float_as_uint(f);
    u += 0x7FFFu + ((u >> 16) & 1u);
    return u >> 16;
}

static __device__ __forceinline__ short8 pack8(float4 a, float4 b){
    short8 r;
    r[0]=(short)f2bf(a.x); r[1]=(short)f2bf(a.y);
    r[2]=(short)f2bf(a.z); r[3]=(short)f2bf(a.w);
    r[4]=(short)f2bf(b.x); r[5]=(short)f2bf(b.y);
    r[6]=(short)f2bf(b.z); r[7]=(short)f2bf(b.w);
    return r;
}

// ---- mask -> bit-packed [b][q][32 words]; dtype sniff merged (per-block:
// int32 bools are all in {0,1}; byte-bools set bytes 1..3 in any 2048 words).
__global__ __launch_bounds__(256) void mask_prep_k(
    const unsigned int* __restrict__ m, unsigned int* __restrict__ bmout)
{
    __shared__ int any_hi;
    const int tid  = threadIdx.x;
    const int lane = tid & 63;
    const unsigned int gbase = blockIdx.x*256u + tid;
    if (tid == 0) any_hi = 0;

    unsigned int wv[8]; unsigned int acc = 0;
    #pragma unroll
    for (int it = 0; it < 8; ++it){
        wv[it] = m[it*262144u + gbase];
        acc |= wv[it];
    }
    __syncthreads();
    if (acc & 0xFFFFFF00u) atomicOr(&any_hi, 1);
    __syncthreads();

    if (any_hi == 0){
        for (int it = 0; it < 32; ++it){
            unsigned int idx = it*262144u + gbase;
            unsigned int v = m[idx];
            unsigned long long bal = __ballot(v != 0u);
            if (lane == 0)
                *(unsigned long long*)(bmout + (idx >> 5)) = bal;
        }
    } else {
        #pragma unroll
        for (int it = 0; it < 8; ++it){
            unsigned int idx = it*262144u + gbase;
            unsigned int v = wv[it];
            unsigned int nib = (v | (v>>7) | (v>>14) | (v>>21)) & 0xFu;
            unsigned int x = nib << ((lane & 7)*4);
            x |= (unsigned int)__shfl_xor((int)x, 1);
            x |= (unsigned int)__shfl_xor((int)x, 2);
            x |= (unsigned int)__shfl_xor((int)x, 4);
            if ((lane & 7) == 0)
                bmout[idx >> 3] = x;
        }
    }
}

// ---------------- QKV projection (3-way split grid) ----------------
__global__ __launch_bounds__(256) void qkv_proj_k(
    const float* __restrict__ nd,
    const float* __restrict__ Wqp, const float* __restrict__ bqp,
    const float* __restrict__ Wkp, const float* __restrict__ bkp,
    const float* __restrict__ Wvp, const float* __restrict__ bvp,
    unsigned short* __restrict__ qout, unsigned short* __restrict__ kout,
    unsigned short* __restrict__ vtout)
{
    __shared__ __align__(16) unsigned short xl[64*264];
    const int tid  = threadIdx.x;
    const int bi   = blockIdx.x;          // 384 = 3 kinds x 128 tiles
    const int kind = bi >> 7;
    const int R0   = (bi & 127) * 64;
    const int b    = R0 >> 10;
    const int n0   = R0 & 1023;

    #pragma unroll
    for (int it = 0; it < 16; ++it){
        int f4 = it*256 + tid;
        int r = f4 >> 6, c4 = f4 & 63;
        float4 v = *(const float4*)(nd + (size_t)(R0+r)*256 + c4*4);
        unsigned int lo = f2bf(v.x) | (f2bf(v.y) << 16);
        unsigned int hi = f2bf(v.z) | (f2bf(v.w) << 16);
        *(uint2*)&xl[r*264 + c4*4] = make_uint2(lo, hi);
    }
    __syncthreads();

    const int lane = tid & 63;
    const int w  = tid >> 6;
    const int ln = lane & 15;
    const int g  = lane >> 4;
    const int ow = w * 64;

    f32x4 acc[4][4];
    #pragma unroll
    for (int a=0;a<4;++a){
        #pragma unroll
        for (int c=0;c<4;++c) acc[a][c] = (f32x4){0.f,0.f,0.f,0.f};
    }

    if (kind < 2){
        const float* W  = kind ? Wkp : Wqp;
        const float* bb = kind ? bkp : bqp;
        unsigned short* op = kind ? kout : qout;
        const float scl = kind ? 1.0f : 0.17677669529663687f;
        for (int kk = 0; kk < 8; ++kk){
            short8 wf[4], xf[4];
            #pragma unroll
            for (int ot=0; ot<4; ++ot){
                const float* wp = W + (size_t)(ow + ot*16 + ln)*256 + kk*32 + g*8;
                wf[ot] = pack8(*(const float4*)wp, *(const float4*)(wp+4));
            }
            #pragma unroll
            for (int nt=0; nt<4; ++nt)
                xf[nt] = *(const short8*)&xl[(nt*16+ln)*264 + kk*32 + g*8];
            #pragma unroll
            for (int ot=0; ot<4; ++ot){
                #pragma unroll
                for (int nt=0; nt<4; ++nt)
                    acc[ot][nt] = MFMA16(wf[ot], xf[nt], acc[ot][nt]);
            }
        }
        #pragma unroll
        for (int ot=0; ot<4; ++ot){
            int o0 = ow + ot*16 + g*4;
            int h = o0 >> 5, d0 = o0 & 31;
            float4 b4 = *(const float4*)(bb + o0);
            #pragma unroll
            for (int nt=0; nt<4; ++nt){
                int n = n0 + nt*16 + ln;
                unsigned int lo = f2bf((acc[ot][nt][0]+b4.x)*scl) | (f2bf((acc[ot][nt][1]+b4.y)*scl)<<16);
                unsigned int hi = f2bf((acc[ot][nt][2]+b4.z)*scl) | (f2bf((acc[ot][nt][3]+b4.w)*scl)<<16);
                *(uint2*)(op + ((size_t)(b*8+h)*1024 + n)*32 + d0) = make_uint2(lo,hi);
            }
        }
    } else {
        for (int kk = 0; kk < 8; ++kk){
            short8 wf[4], xf[4];
            #pragma unroll
            for (int ot=0; ot<4; ++ot){
                const float* wp = Wvp + (size_t)(ow + ot*16 + ln)*256 + kk*32 + g*8;
                wf[ot] = pack8(*(const float4*)wp, *(const float4*)(wp+4));
            }
            #pragma unroll
            for (int nt=0; nt<4; ++nt)
                xf[nt] = *(const short8*)&xl[(nt*16+ln)*264 + kk*32 + g*8];
            #pragma unroll
            for (int nt=0; nt<4; ++nt){
                #pragma unroll
                for (int ot=0; ot<4; ++ot)
                    acc[nt][ot] = MFMA16(xf[nt], wf[ot], acc[nt][ot]);
            }
        }
        #pragma unroll
        for (int nt=0; nt<4; ++nt){
            int nb = n0 + nt*16 + g*4;
            #pragma unroll
            for (int ot=0; ot<4; ++ot){
                int o = ow + ot*16 + ln;
                int h = o >> 5, d = o & 31;
                float bvv = bvp[o];
                unsigned int lo = f2bf(acc[nt][ot][0]+bvv) | (f2bf(acc[nt][ot][1]+bvv)<<16);
                unsigned int hi = f2bf(acc[nt][ot][2]+bvv) | (f2bf(acc[nt][ot][3]+bvv)<<16);
                *(uint2*)(vtout + ((size_t)(b*8+h)*32 + d)*1024 + nb) = make_uint2(lo,hi);
            }
        }
    }
}

// ---------------- Fused attention v3: direct fp32 bias, zero LDS/barriers --
// Grid 512 = b(8) x qt(64); 256 thr = 4 waves; wave w = head pair (2w, 2w+1).
// Lane (q=ln, keys 8g+j) loads bias as float2 (h=2w,2w+1) -> both floats used;
// each 64B bias line fully consumed by this block's 4 waves (same CU/L1/L2)
// => bias crosses HBM exactly once, no staging pass, no LDS, no barriers.
// kperm zero-shuffle P-frag (r9/r10/r12-verified), fixed-max softmax (r8+),
// bit-packed mask. 2-deep A/B register pipeline (r12-verified).
__global__ __launch_bounds__(256, 2) void attn3_k(
    const unsigned short* __restrict__ qbuf, const unsigned short* __restrict__ kbuf,
    const unsigned short* __restrict__ vtbuf, const float* __restrict__ bias,
    const unsigned int* __restrict__ bm, unsigned short* __restrict__ ab)
{
    const int tid  = threadIdx.x;
    const int bi   = blockIdx.x;        // 512 = 8 b * 64 q-tiles
    const int b    = bi >> 6;
    const int q0   = (bi & 63) * 16;
    const int lane = tid & 63;
    const int w    = tid >> 6;          // wave = head pair
    const int ln   = lane & 15;
    const int g    = lane >> 4;
    const int h0   = 2*w, h1 = 2*w + 1;

    const short8 qf0 = *(const short8*)(qbuf + ((size_t)(b*8+h0)*1024 + q0 + ln)*32 + g*8);
    const short8 qf1 = *(const short8*)(qbuf + ((size_t)(b*8+h1)*1024 + q0 + ln)*32 + g*8);

    // kperm: tile-0 row ln -> key 8*(ln>>2)+(ln&3) = 8g+r in S^T; tile-1 +4
    const int kperm = ((ln >> 2) << 3) + (ln & 3);
    const unsigned short* kpA = kbuf + ((size_t)(b*8+h0)*1024 + kperm)*32 + g*8;
    const unsigned short* kpB = kbuf + ((size_t)(b*8+h1)*1024 + kperm)*32 + g*8;
    const unsigned short* vpA = vtbuf + ((size_t)(b*8+h0)*32 + ln)*1024 + g*8;
    const unsigned short* vpB = vtbuf + ((size_t)(b*8+h1)*32 + ln)*1024 + g*8;
    // bias[b][q][k][h] fp32; float2 at (q0+ln, k=c*32+8g+j, h=2w..2w+1)
    const float* bp = bias + (((size_t)(b*1024 + q0 + ln)*1024) + 8*g)*8 + h0;
    const unsigned int* bmp = bm + (size_t)(b*1024 + q0 + ln)*32;

    f32x4 acc00 = (f32x4){0.f,0.f,0.f,0.f};   // head0, d 0..15
    f32x4 acc01 = (f32x4){0.f,0.f,0.f,0.f};   // head0, d 16..31
    f32x4 acc10 = (f32x4){0.f,0.f,0.f,0.f};
    f32x4 acc11 = (f32x4){0.f,0.f,0.f,0.f};
    float lsum0 = 0.f, lsum1 = 0.f;
    const f32x4 z4 = {0.f,0.f,0.f,0.f};

    short8 k0A,k1A,k2A,k3A, v0A,v1A,v2A,v3A;
    short8 k0B,k1B,k2B,k3B, v0B,v1B,v2B,v3B;
    float2 bb0A,bb1A,bb2A,bb3A,bb4A,bb5A,bb6A,bb7A;
    float2 bb0B,bb1B,bb2B,bb3B,bb4B,bb5B,bb6B,bb7B;
    unsigned int bmA, bmB;

#define LOADC(S, cc) do { int c_ = (cc); \
    k0##S = *(const short8*)(kpA + c_*1024); \
    k1##S = *(const short8*)(kpA + c_*1024 + 128); \
    k2##S = *(const short8*)(kpB + c_*1024); \
    k3##S = *(const short8*)(kpB + c_*1024 + 128); \
    v0##S = *(const short8*)(vpA + c_*32); \
    v1##S = *(const short8*)(vpA + c_*32 + 16*1024); \
    v2##S = *(const short8*)(vpB + c_*32); \
    v3##S = *(const short8*)(vpB + c_*32 + 16*1024); \
    bb0##S = *(const float2*)(bp + (size_t)(c_*32+0)*8); \
    bb1##S = *(const float2*)(bp + (size_t)(c_*32+1)*8); \
    bb2##S = *(const float2*)(bp + (size_t)(c_*32+2)*8); \
    bb3##S = *(const float2*)(bp + (size_t)(c_*32+3)*8); \
    bb4##S = *(const float2*)(bp + (size_t)(c_*32+4)*8); \
    bb5##S = *(const float2*)(bp + (size_t)(c_*32+5)*8); \
    bb6##S = *(const float2*)(bp + (size_t)(c_*32+6)*8); \
    bb7##S = *(const float2*)(bp + (size_t)(c_*32+7)*8); \
    bm##S = bmp[c_]; } while(0)

#define COMPC(S) do { \
    unsigned int mb_ = bm##S >> (g*8); \
    f32x4 s0 = MFMA16(k0##S, qf0, z4); \
    f32x4 s1 = MFMA16(k1##S, qf0, z4); \
    f32x4 s2 = MFMA16(k2##S, qf1, z4); \
    f32x4 s3 = MFMA16(k3##S, qf1, z4); \
    float e0 = __expf(s0[0] + bb0##S.x); e0 = ((mb_>>0)&1u) ? 0.f : e0; \
    float e1 = __expf(s0[1] + bb1##S.x); e1 = ((mb_>>1)&1u) ? 0.f : e1; \
    float e2 = __expf(s0[2] + bb2##S.x); e2 = ((mb_>>2)&1u) ? 0.f : e2; \
    float e3 = __expf(s0[3] + bb3##S.x); e3 = ((mb_>>3)&1u) ? 0.f : e3; \
    float e4 = __expf(s1[0] + bb4##S.x); e4 = ((mb_>>4)&1u) ? 0.f : e4; \
    float e5 = __expf(s1[1] + bb5##S.x); e5 = ((mb_>>5)&1u) ? 0.f : e5; \
    float e6 = __expf(s1[2] + bb6##S.x); e6 = ((mb_>>6)&1u) ? 0.f : e6; \
    float e7 = __expf(s1[3] + bb7##S.x); e7 = ((mb_>>7)&1u) ? 0.f : e7; \
    float f0 = __expf(s2[0] + bb0##S.y); f0 = ((mb_>>0)&1u) ? 0.f : f0; \
    float f1 = __expf(s2[1] + bb1##S.y); f1 = ((mb_>>1)&1u) ? 0.f : f1; \
    float f2 = __expf(s2[2] + bb2##S.y); f2 = ((mb_>>2)&1u) ? 0.f : f2; \
    float f3 = __expf(s2[3] + bb3##S.y); f3 = ((mb_>>3)&1u) ? 0.f : f3; \
    float f4 = __expf(s3[0] + bb4##S.y); f4 = ((mb_>>4)&1u) ? 0.f : f4; \
    float f5 = __expf(s3[1] + bb5##S.y); f5 = ((mb_>>5)&1u) ? 0.f : f5; \
    float f6 = __expf(s3[2] + bb6##S.y); f6 = ((mb_>>6)&1u) ? 0.f : f6; \
    float f7 = __expf(s3[3] + bb7##S.y); f7 = ((mb_>>7)&1u) ? 0.f : f7; \
    lsum0 += ((e0+e1)+(e2+e3)) + ((e4+e5)+(e6+e7)); \
    lsum1 += ((f0+f1)+(f2+f3)) + ((f4+f5)+(f6+f7)); \
    int4 pw0 = make_int4( \
        (int)(f2bf(e0) | (f2bf(e1)<<16)), (int)(f2bf(e2) | (f2bf(e3)<<16)), \
        (int)(f2bf(e4) | (f2bf(e5)<<16)), (int)(f2bf(e6) | (f2bf(e7)<<16))); \
    int4 pw1 = make_int4( \
        (int)(f2bf(f0) | (f2bf(f1)<<16)), (int)(f2bf(f2) | (f2bf(f3)<<16)), \
        (int)(f2bf(f4) | (f2bf(f5)<<16)), (int)(f2bf(f6) | (f2bf(f7)<<16))); \
    short8 pf0 = *(short8*)&pw0; \
    short8 pf1 = *(short8*)&pw1; \
    acc00 = MFMA16(v0##S, pf0, acc00); \
    acc01 = MFMA16(v1##S, pf0, acc01); \
    acc10 = MFMA16(v2##S, pf1, acc10); \
    acc11 = MFMA16(v3##S, pf1, acc11); } while(0)

    LOADC(A, 0);
    bmA &= ~1u;                         // col 0 force-unmasked (chunk 0, bit 0)
    #pragma unroll 1
    for (int c = 0; c < 32; c += 2){
        LOADC(B, c + 1);                // in flight during COMPC(A)
        COMPC(A);
        if (c + 2 < 32) LOADC(A, c + 2);
        COMPC(B);
    }

    // epilogue: per-head denominator reduce + normalized bf16 store
    {
        float ps0 = lsum0;
        ps0 += __shfl_xor(ps0, 16);
        ps0 += __shfl_xor(ps0, 32);
        float inv0 = 1.0f / ps0;
        size_t orow = ((size_t)(b*1024 + q0 + ln))*256 + h0*32;
        unsigned int lo = f2bf(acc00[0]*inv0) | (f2bf(acc00[1]*inv0)<<16);
        unsigned int hi = f2bf(acc00[2]*inv0) | (f2bf(acc00[3]*inv0)<<16);
        *(uint2*)(ab + orow + g*4) = make_uint2(lo,hi);
        lo = f2bf(acc01[0]*inv0) | (f2bf(acc01[1]*inv0)<<16);
        hi = f2bf(acc01[2]*inv0) | (f2bf(acc01[3]*inv0)<<16);
        *(uint2*)(ab + orow + 16 + g*4) = make_uint2(lo,hi);

        float ps1 = lsum1;
        ps1 += __shfl_xor(ps1, 16);
        ps1 += __shfl_xor(ps1, 32);
        float inv1 = 1.0f / ps1;
        size_t orow1 = ((size_t)(b*1024 + q0 + ln))*256 + h1*32;
        lo = f2bf(acc10[0]*inv1) | (f2bf(acc10[1]*inv1)<<16);
        hi = f2bf(acc10[2]*inv1) | (f2bf(acc10[3]*inv1)<<16);
        *(uint2*)(ab + orow1 + g*4) = make_uint2(lo,hi);
        lo = f2bf(acc11[0]*inv1) | (f2bf(acc11[1]*inv1)<<16);
        hi = f2bf(acc11[2]*inv1) | (f2bf(acc11[3]*inv1)<<16);
        *(uint2*)(ab + orow1 + 16 + g*4) = make_uint2(lo,hi);
    }
#undef LOADC
#undef COMPC
}

// ---------------- Output projection (32-row tiles) ----------------
__global__ __launch_bounds__(256) void oproj_k(
    const unsigned short* __restrict__ ab, const float* __restrict__ Wop,
    const float* __restrict__ bop, float* __restrict__ out)
{
    __shared__ __align__(16) unsigned short al[32*264];
    const int tid = threadIdx.x;
    const int R0 = blockIdx.x * 32;   // 256 blocks
    #pragma unroll
    for (int it=0; it<4; ++it){
        int f8 = it*256 + tid;
        int r = f8 >> 5, c8 = f8 & 31;
        *(short8*)&al[r*264 + c8*8] = *(const short8*)(ab + (size_t)(R0+r)*256 + c8*8);
    }
    __syncthreads();
    const int lane = tid & 63;
    const int w = tid >> 6, ln = lane & 15, g = lane >> 4;
    const int ow = w*64;
    f32x4 acc[4][2];
    #pragma unroll
    for (int a=0;a<4;++a){ acc[a][0]=(f32x4){0.f,0.f,0.f,0.f}; acc[a][1]=(f32x4){0.f,0.f,0.f,0.f}; }
    for (int kk=0;kk<8;++kk){
        short8 wf[4], xf[2];
        #pragma unroll
        for (int ot=0;ot<4;++ot){
            const float* wp = Wop + (size_t)(ow+ot*16+ln)*256 + kk*32 + g*8;
            wf[ot] = pack8(*(const float4*)wp, *(const float4*)(wp+4));
        }
        #pragma unroll
        for (int nt=0;nt<2;++nt)
            xf[nt] = *(const short8*)&al[(nt*16+ln)*264 + kk*32 + g*8];
        #pragma unroll
        for (int ot=0;ot<4;++ot){
            #pragma unroll
            for (int nt=0;nt<2;++nt)
                acc[ot][nt] = MFMA16(wf[ot], xf[nt], acc[ot][nt]);
        }
    }
    #pragma unroll
    for (int ot=0;ot<4;++ot){
        int o0 = ow + ot*16 + g*4;
        float4 b4 = *(const float4*)(bop + o0);
        #pragma unroll
        for (int nt=0;nt<2;++nt){
            int n = R0 + nt*16 + ln;
            float4 res;
            res.x = acc[ot][nt][0] + b4.x;
            res.y = acc[ot][nt][1] + b4.y;
            res.z = acc[ot][nt][2] + b4.z;
            res.w = acc[ot][nt][3] + b4.w;
            *(float4*)(out + (size_t)n*256 + o0) = res;
        }
    }
}

extern "C" void kernel_launch(void* const* d_in, const int* in_sizes, int n_in,
                              void* d_out, int out_size, void* d_ws, size_t ws_size,
                              hipStream_t stream)
{
    (void)in_sizes; (void)n_in; (void)out_size; (void)ws_size;
    const float* nd   = (const float*)d_in[0];
    // d_in[1] = N scalar (compile-time 1024 here)
    const float* bias = (const float*)d_in[2];
    const int* mask   = (const int*)d_in[3];
    const float* Wq = (const float*)d_in[4];
    const float* bq = (const float*)d_in[5];
    const float* Wk = (const float*)d_in[6];
    const float* bk = (const float*)d_in[7];
    const float* Wv = (const float*)d_in[8];
    const float* bv = (const float*)d_in[9];
    const float* Wo = (const float*)d_in[10];
    const float* bo = (const float*)d_in[11];
    float* out = (float*)d_out;

    const size_t ELEMS = (size_t)8*8*1024*32;   // 2M bf16 per buffer
    unsigned short* qb  = (unsigned short*)d_ws;
    unsigned short* kb  = qb  + ELEMS;
    unsigned short* vtb = kb  + ELEMS;
    unsigned short* ab  = vtb + ELEMS;
    unsigned int* bmw   = (unsigned int*)(ab + ELEMS);  // 1MB bitmask

    mask_prep_k<<<1024, 256, 0, stream>>>((const unsigned int*)mask, bmw);
    qkv_proj_k<<<384, 256, 0, stream>>>(nd, Wq, bq, Wk, bk, Wv, bv, qb, kb, vtb);
    attn3_k<<<512, 256, 0, stream>>>(qb, kb, vtb, bias, bmw, ab);
    oproj_k<<<256, 256, 0, stream>>>(ab, Wo, bo, out);
}

// Round 14
// 139.500 us; speedup vs baseline: 1.4281x; 1.4281x over previous
//
#include <hip/hip_runtime.h>
#include <hip/hip_bf16.h>

typedef __attribute__((ext_vector_type(8))) short short8;
typedef __attribute__((ext_vector_type(4))) float f32x4;

#define MFMA16(a,b,c) __builtin_amdgcn_mfma_f32_16x16x32_bf16((a),(b),(c),0,0,0)

static __device__ __forceinline__ unsigned int f2bf(float f){
    unsigned int u = __float_as_uint(f);
    u += 0x7FFFu + ((u >> 16) & 1u);
    return u >> 16;
}

static __device__ __forceinline__ short8 pack8(float4 a, float4 b){
    short8 r;
    r[0]=(short)f2bf(a.x); r[1]=(short)f2bf(a.y);
    r[2]=(short)f2bf(a.z); r[3]=(short)f2bf(a.w);
    r[4]=(short)f2bf(b.x); r[5]=(short)f2bf(b.y);
    r[6]=(short)f2bf(b.z); r[7]=(short)f2bf(b.w);
    return r;
}

// ---- mask -> bit-packed [b][q][32 words]; dtype sniff merged.
__global__ __launch_bounds__(256) void mask_prep_k(
    const unsigned int* __restrict__ m, unsigned int* __restrict__ bmout)
{
    __shared__ int any_hi;
    const int tid  = threadIdx.x;
    const int lane = tid & 63;
    const unsigned int gbase = blockIdx.x*256u + tid;
    if (tid == 0) any_hi = 0;

    unsigned int wv[8]; unsigned int acc = 0;
    #pragma unroll
    for (int it = 0; it < 8; ++it){
        wv[it] = m[it*262144u + gbase];
        acc |= wv[it];
    }
    __syncthreads();
    if (acc & 0xFFFFFF00u) atomicOr(&any_hi, 1);
    __syncthreads();

    if (any_hi == 0){
        for (int it = 0; it < 32; ++it){
            unsigned int idx = it*262144u + gbase;
            unsigned int v = m[idx];
            unsigned long long bal = __ballot(v != 0u);
            if (lane == 0)
                *(unsigned long long*)(bmout + (idx >> 5)) = bal;
        }
    } else {
        #pragma unroll
        for (int it = 0; it < 8; ++it){
            unsigned int idx = it*262144u + gbase;
            unsigned int v = wv[it];
            unsigned int nib = (v | (v>>7) | (v>>14) | (v>>21)) & 0xFu;
            unsigned int x = nib << ((lane & 7)*4);
            x |= (unsigned int)__shfl_xor((int)x, 1);
            x |= (unsigned int)__shfl_xor((int)x, 2);
            x |= (unsigned int)__shfl_xor((int)x, 4);
            if ((lane & 7) == 0)
                bmout[idx >> 3] = x;
        }
    }
}

// ---------------- QKV projection (3-way split grid) ----------------
__global__ __launch_bounds__(256) void qkv_proj_k(
    const float* __restrict__ nd,
    const float* __restrict__ Wqp, const float* __restrict__ bqp,
    const float* __restrict__ Wkp, const float* __restrict__ bkp,
    const float* __restrict__ Wvp, const float* __restrict__ bvp,
    unsigned short* __restrict__ qout, unsigned short* __restrict__ kout,
    unsigned short* __restrict__ vtout)
{
    __shared__ __align__(16) unsigned short xl[64*264];
    const int tid  = threadIdx.x;
    const int bi   = blockIdx.x;          // 384 = 3 kinds x 128 tiles
    const int kind = bi >> 7;
    const int R0   = (bi & 127) * 64;
    const int b    = R0 >> 10;
    const int n0   = R0 & 1023;

    #pragma unroll
    for (int it = 0; it < 16; ++it){
        int f4 = it*256 + tid;
        int r = f4 >> 6, c4 = f4 & 63;
        float4 v = *(const float4*)(nd + (size_t)(R0+r)*256 + c4*4);
        unsigned int lo = f2bf(v.x) | (f2bf(v.y) << 16);
        unsigned int hi = f2bf(v.z) | (f2bf(v.w) << 16);
        *(uint2*)&xl[r*264 + c4*4] = make_uint2(lo, hi);
    }
    __syncthreads();

    const int lane = tid & 63;
    const int w  = tid >> 6;
    const int ln = lane & 15;
    const int g  = lane >> 4;
    const int ow = w * 64;

    f32x4 acc[4][4];
    #pragma unroll
    for (int a=0;a<4;++a){
        #pragma unroll
        for (int c=0;c<4;++c) acc[a][c] = (f32x4){0.f,0.f,0.f,0.f};
    }

    if (kind < 2){
        const float* W  = kind ? Wkp : Wqp;
        const float* bb = kind ? bkp : bqp;
        unsigned short* op = kind ? kout : qout;
        const float scl = kind ? 1.0f : 0.17677669529663687f;
        for (int kk = 0; kk < 8; ++kk){
            short8 wf[4], xf[4];
            #pragma unroll
            for (int ot=0; ot<4; ++ot){
                const float* wp = W + (size_t)(ow + ot*16 + ln)*256 + kk*32 + g*8;
                wf[ot] = pack8(*(const float4*)wp, *(const float4*)(wp+4));
            }
            #pragma unroll
            for (int nt=0; nt<4; ++nt)
                xf[nt] = *(const short8*)&xl[(nt*16+ln)*264 + kk*32 + g*8];
            #pragma unroll
            for (int ot=0; ot<4; ++ot){
                #pragma unroll
                for (int nt=0; nt<4; ++nt)
                    acc[ot][nt] = MFMA16(wf[ot], xf[nt], acc[ot][nt]);
            }
        }
        #pragma unroll
        for (int ot=0; ot<4; ++ot){
            int o0 = ow + ot*16 + g*4;
            int h = o0 >> 5, d0 = o0 & 31;
            float4 b4 = *(const float4*)(bb + o0);
            #pragma unroll
            for (int nt=0; nt<4; ++nt){
                int n = n0 + nt*16 + ln;
                unsigned int lo = f2bf((acc[ot][nt][0]+b4.x)*scl) | (f2bf((acc[ot][nt][1]+b4.y)*scl)<<16);
                unsigned int hi = f2bf((acc[ot][nt][2]+b4.z)*scl) | (f2bf((acc[ot][nt][3]+b4.w)*scl)<<16);
                *(uint2*)(op + ((size_t)(b*8+h)*1024 + n)*32 + d0) = make_uint2(lo,hi);
            }
        }
    } else {
        for (int kk = 0; kk < 8; ++kk){
            short8 wf[4], xf[4];
            #pragma unroll
            for (int ot=0; ot<4; ++ot){
                const float* wp = Wvp + (size_t)(ow + ot*16 + ln)*256 + kk*32 + g*8;
                wf[ot] = pack8(*(const float4*)wp, *(const float4*)(wp+4));
            }
            #pragma unroll
            for (int nt=0; nt<4; ++nt)
                xf[nt] = *(const short8*)&xl[(nt*16+ln)*264 + kk*32 + g*8];
            #pragma unroll
            for (int nt=0; nt<4; ++nt){
                #pragma unroll
                for (int ot=0; ot<4; ++ot)
                    acc[nt][ot] = MFMA16(xf[nt], wf[ot], acc[nt][ot]);
            }
        }
        #pragma unroll
        for (int nt=0; nt<4; ++nt){
            int nb = n0 + nt*16 + g*4;
            #pragma unroll
            for (int ot=0; ot<4; ++ot){
                int o = ow + ot*16 + ln;
                int h = o >> 5, d = o & 31;
                float bvv = bvp[o];
                unsigned int lo = f2bf(acc[nt][ot][0]+bvv) | (f2bf(acc[nt][ot][1]+bvv)<<16);
                unsigned int hi = f2bf(acc[nt][ot][2]+bvv) | (f2bf(acc[nt][ot][3]+bvv)<<16);
                *(uint2*)(vtout + ((size_t)(b*8+h)*32 + d)*1024 + nb) = make_uint2(lo,hi);
            }
        }
    }
}

// ---------------- Fused biased-masked attention (r14) ----------------
// r11's proven loop (64-key chunks, 2 drain barriers, snapshot-before-reload,
// 8 waves = 8 heads, 16 q) + r13's proven kperm zero-shuffle compute +
// read-optimal bias LDS [8h][16q][68pad]: staging coalesced (4xfloat4/thr),
// per-lane bias = 2x ds_read_b128 per 32-key half (keys 8g..8g+7 contiguous).
__global__ __launch_bounds__(512, 4) void attn_k(
    const unsigned short* __restrict__ qbuf, const unsigned short* __restrict__ kbuf,
    const unsigned short* __restrict__ vtbuf, const float* __restrict__ bias,
    const unsigned int* __restrict__ bm, unsigned short* __restrict__ ab)
{
    __shared__ __align__(16) float bs[8704];   // [8h][16q][68] words = 34.8 KB
    const int tid  = threadIdx.x;
    const int bi   = blockIdx.x;        // 512 = 8 b * 64 q-tiles
    const int b    = bi >> 6;
    const int q0   = (bi & 63) * 16;
    const int lane = tid & 63;
    const int w    = tid >> 6;          // wave = head
    const int ln   = lane & 15;
    const int g    = lane >> 4;

    // Q fragment (B-operand): col=q=ln, k=d=g*8..
    const short8 qf = *(const short8*)(qbuf + ((size_t)(b*8+w)*1024 + q0 + ln)*32 + g*8);

    // kperm: tile-local row ln -> key 8*(ln>>2)+(ln&3); S^T keys/lane = 8g+j
    const int kperm = ((ln >> 2) << 3) + (ln & 3);
    const unsigned short* kp = kbuf  + ((size_t)(b*8+w)*1024 + kperm)*32 + g*8;
    const unsigned short* vp = vtbuf + ((size_t)(b*8+w)*32   + ln)*1024 + g*8;
    const unsigned int*  bmp = bm + (size_t)(b*1024 + q0 + ln)*32;

    // bias staging: thread t covers q'=t>>5, float4s idx=it*32+(t&31) of the
    // 512-float row-chunk; global float-off = idx*4 (k'=idx>>1, h'=(t&1)*4)
    const int sq  = tid >> 5;
    const float* bgp = bias + (size_t)(b*1024 + q0 + sq)*8192 + (tid & 31)*4;
    const int hqb = (tid & 1)*4*1088 + sq*68;          // LDS write base (words)
    const int kpw = (tid & 31) >> 1;                   // k' within 16-block
    // bias read base: [h=w][q=ln][k]: 2x b128 per half at +8g, +8g+4
    const int rb0 = w*1088 + ln*68 + 8*g;

    f32x4 acc0 = (f32x4){0.f,0.f,0.f,0.f};
    f32x4 acc1 = (f32x4){0.f,0.f,0.f,0.f};
    float lsum = 0.f;
    const f32x4 z4 = {0.f,0.f,0.f,0.f};

    float4 br0, br1, br2, br3;
    short8 kn0, kn1, kn2, kn3;
    unsigned int bm0, bm1;

#define LOAD_ALL(cc) do { int c_ = (cc); \
    br0 = *(const float4*)(bgp + (size_t)c_*512); \
    br1 = *(const float4*)(bgp + (size_t)c_*512 + 128); \
    br2 = *(const float4*)(bgp + (size_t)c_*512 + 256); \
    br3 = *(const float4*)(bgp + (size_t)c_*512 + 384); \
    kn0 = *(const short8*)(kp + c_*2048); \
    kn1 = *(const short8*)(kp + c_*2048 + 128); \
    kn2 = *(const short8*)(kp + c_*2048 + 1024); \
    kn3 = *(const short8*)(kp + c_*2048 + 1152); \
    bm0 = bmp[2*c_]; bm1 = bmp[2*c_+1]; } while(0)

#define STAGE1(R, IT) do { int kw_ = (IT)*16 + kpw; \
    bs[hqb        + kw_] = R.x; \
    bs[hqb + 1088 + kw_] = R.y; \
    bs[hqb + 2176 + kw_] = R.z; \
    bs[hqb + 3264 + kw_] = R.w; } while(0)

// one 32-key half (keys base=kh*32): kperm'd QK^T, b128 bias, exp, PV
#define CHUNK_HALF(K0, K1, BMW, KH, VOFF) do { \
    f32x4 s0 = MFMA16(K0, qf, z4);   /* keys base+8g+0..3 */ \
    f32x4 s1 = MFMA16(K1, qf, z4);   /* keys base+8g+4..7 */ \
    f32x4 blo = *(const f32x4*)&bs[rb0 + (KH)*32]; \
    f32x4 bhi = *(const f32x4*)&bs[rb0 + (KH)*32 + 4]; \
    short8 vf0 = *(const short8*)(vp + (VOFF)); \
    short8 vf1 = *(const short8*)(vp + (VOFF) + 16*1024); \
    unsigned int mb_ = (BMW) >> (g*8); \
    float e0 = __expf(s0[0] + blo[0]); e0 = ((mb_>>0)&1u) ? 0.f : e0; \
    float e1 = __expf(s0[1] + blo[1]); e1 = ((mb_>>1)&1u) ? 0.f : e1; \
    float e2 = __expf(s0[2] + blo[2]); e2 = ((mb_>>2)&1u) ? 0.f : e2; \
    float e3 = __expf(s0[3] + blo[3]); e3 = ((mb_>>3)&1u) ? 0.f : e3; \
    float e4 = __expf(s1[0] + bhi[0]); e4 = ((mb_>>4)&1u) ? 0.f : e4; \
    float e5 = __expf(s1[1] + bhi[1]); e5 = ((mb_>>5)&1u) ? 0.f : e5; \
    float e6 = __expf(s1[2] + bhi[2]); e6 = ((mb_>>6)&1u) ? 0.f : e6; \
    float e7 = __expf(s1[3] + bhi[3]); e7 = ((mb_>>7)&1u) ? 0.f : e7; \
    lsum += ((e0+e1)+(e2+e3)) + ((e4+e5)+(e6+e7)); \
    int4 pw_ = make_int4( \
        (int)(f2bf(e0) | (f2bf(e1)<<16)), (int)(f2bf(e2) | (f2bf(e3)<<16)), \
        (int)(f2bf(e4) | (f2bf(e5)<<16)), (int)(f2bf(e6) | (f2bf(e7)<<16))); \
    short8 pf_ = *(short8*)&pw_; \
    acc0 = MFMA16(vf0, pf_, acc0); \
    acc1 = MFMA16(vf1, pf_, acc1); } while(0)

    // prologue: chunk 0
    LOAD_ALL(0);
    bm0 &= ~1u;                         // col 0 force-unmasked

    #pragma unroll 1
    for (int cc = 0; cc < 16; ++cc){
        // stage bias chunk cc (16 coalesced-sourced scalar writes)
        STAGE1(br0, 0); STAGE1(br1, 1); STAGE1(br2, 2); STAGE1(br3, 3);
        // snapshot K/mask of current chunk BEFORE reload (r6 lesson)
        short8 ck0 = kn0, ck1 = kn1, ck2 = kn2, ck3 = kn3;
        unsigned int cb0 = bm0, cb1 = bm1;
        if (cc + 1 < 16) LOAD_ALL(cc + 1);
        __syncthreads();

        CHUNK_HALF(ck0, ck1, cb0, 0, cc*64);
        CHUNK_HALF(ck2, ck3, cb1, 1, cc*64 + 32);
        __syncthreads();
    }

    float ps = lsum;
    ps += __shfl_xor(ps, 16);
    ps += __shfl_xor(ps, 32);
    float inv = 1.0f / ps;
    {
        int n = q0 + ln;
        unsigned int lo0 = f2bf(acc0[0]*inv) | (f2bf(acc0[1]*inv)<<16);
        unsigned int hi0 = f2bf(acc0[2]*inv) | (f2bf(acc0[3]*inv)<<16);
        *(uint2*)(ab + ((size_t)(b*1024 + n))*256 + w*32 + g*4) = make_uint2(lo0,hi0);
        unsigned int lo1 = f2bf(acc1[0]*inv) | (f2bf(acc1[1]*inv)<<16);
        unsigned int hi1 = f2bf(acc1[2]*inv) | (f2bf(acc1[3]*inv)<<16);
        *(uint2*)(ab + ((size_t)(b*1024 + n))*256 + w*32 + 16 + g*4) = make_uint2(lo1,hi1);
    }
#undef LOAD_ALL
#undef STAGE1
#undef CHUNK_HALF
}

// ---------------- Output projection (32-row tiles) ----------------
__global__ __launch_bounds__(256) void oproj_k(
    const unsigned short* __restrict__ ab, const float* __restrict__ Wop,
    const float* __restrict__ bop, float* __restrict__ out)
{
    __shared__ __align__(16) unsigned short al[32*264];
    const int tid = threadIdx.x;
    const int R0 = blockIdx.x * 32;   // 256 blocks
    #pragma unroll
    for (int it=0; it<4; ++it){
        int f8 = it*256 + tid;
        int r = f8 >> 5, c8 = f8 & 31;
        *(short8*)&al[r*264 + c8*8] = *(const short8*)(ab + (size_t)(R0+r)*256 + c8*8);
    }
    __syncthreads();
    const int lane = tid & 63;
    const int w = tid >> 6, ln = lane & 15, g = lane >> 4;
    const int ow = w*64;
    f32x4 acc[4][2];
    #pragma unroll
    for (int a=0;a<4;++a){ acc[a][0]=(f32x4){0.f,0.f,0.f,0.f}; acc[a][1]=(f32x4){0.f,0.f,0.f,0.f}; }
    for (int kk=0;kk<8;++kk){
        short8 wf[4], xf[2];
        #pragma unroll
        for (int ot=0;ot<4;++ot){
            const float* wp = Wop + (size_t)(ow+ot*16+ln)*256 + kk*32 + g*8;
            wf[ot] = pack8(*(const float4*)wp, *(const float4*)(wp+4));
        }
        #pragma unroll
        for (int nt=0;nt<2;++nt)
            xf[nt] = *(const short8*)&al[(nt*16+ln)*264 + kk*32 + g*8];
        #pragma unroll
        for (int ot=0;ot<4;++ot){
            #pragma unroll
            for (int nt=0;nt<2;++nt)
                acc[ot][nt] = MFMA16(wf[ot], xf[nt], acc[ot][nt]);
        }
    }
    #pragma unroll
    for (int ot=0;ot<4;++ot){
        int o0 = ow + ot*16 + g*4;
        float4 b4 = *(const float4*)(bop + o0);
        #pragma unroll
        for (int nt=0;nt<2;++nt){
            int n = R0 + nt*16 + ln;
            float4 res;
            res.x = acc[ot][nt][0] + b4.x;
            res.y = acc[ot][nt][1] + b4.y;
            res.z = acc[ot][nt][2] + b4.z;
            res.w = acc[ot][nt][3] + b4.w;
            *(float4*)(out + (size_t)n*256 + o0) = res;
        }
    }
}

extern "C" void kernel_launch(void* const* d_in, const int* in_sizes, int n_in,
                              void* d_out, int out_size, void* d_ws, size_t ws_size,
                              hipStream_t stream)
{
    (void)in_sizes; (void)n_in; (void)out_size; (void)ws_size;
    const float* nd   = (const float*)d_in[0];
    // d_in[1] = N scalar (compile-time 1024 here)
    const float* bias = (const float*)d_in[2];
    const int* mask   = (const int*)d_in[3];
    const float* Wq = (const float*)d_in[4];
    const float* bq = (const float*)d_in[5];
    const float* Wk = (const float*)d_in[6];
    const float* bk = (const float*)d_in[7];
    const float* Wv = (const float*)d_in[8];
    const float* bv = (const float*)d_in[9];
    const float* Wo = (const float*)d_in[10];
    const float* bo = (const float*)d_in[11];
    float* out = (float*)d_out;

    const size_t ELEMS = (size_t)8*8*1024*32;   // 2M bf16 per buffer
    unsigned short* qb  = (unsigned short*)d_ws;
    unsigned short* kb  = qb  + ELEMS;
    unsigned short* vtb = kb  + ELEMS;
    unsigned short* ab  = vtb + ELEMS;
    unsigned int* bmw   = (unsigned int*)(ab + ELEMS);  // 1MB bitmask

    mask_prep_k<<<1024, 256, 0, stream>>>((const unsigned int*)mask, bmw);
    qkv_proj_k<<<384, 256, 0, stream>>>(nd, Wq, bq, Wk, bk, Wv, bv, qb, kb, vtb);
    attn_k<<<512, 512, 0, stream>>>(qb, kb, vtb, bias, bmw, ab);
    oproj_k<<<256, 256, 0, stream>>>(ab, Wo, bo, out);
}